// Round 1
// baseline (520.617 us; speedup 1.0000x reference)
//
#include <hip/hip_runtime.h>

// Problem constants (B,C,H,W = 4,64,64,64; d = 8)
#define BB 4
#define CC 64
#define HH 64
#define WW 64
#define NN 4096   // H*W
#define DD 8

// ws layout (floats):
//   qT [B][8][N]  at 0            (131072 floats)
//   kT [B][8][N]  at 131072       (131072 floats)
//   vT [B][N][C]  at 262144       (1048576 floats)
// total 1,310,720 floats = 5.25 MB

// ---------------------------------------------------------------------------
// Kernel 1: QKV projection (1x1 convs). One thread per (b,n); blockIdx&3
// selects which 16 v-channels this block computes (q/k only on eblk==0).
// ---------------------------------------------------------------------------
__global__ __launch_bounds__(256) void qkv_kernel(
    const float* __restrict__ x,
    const float* __restrict__ Wq, const float* __restrict__ bq,
    const float* __restrict__ Wk, const float* __restrict__ bk,
    const float* __restrict__ Wv, const float* __restrict__ bv,
    float* __restrict__ qT, float* __restrict__ kT, float* __restrict__ vT)
{
    const int eblk = blockIdx.x & 3;
    const int gid  = blockIdx.x >> 2;           // 0..63
    const int idx  = gid * 256 + threadIdx.x;   // 0..16383 = b*N + n
    const int b    = idx >> 12;
    const int n    = idx & (NN - 1);

    const float* xb = x + (size_t)b * CC * NN + n;
    float xv[CC];
#pragma unroll
    for (int c = 0; c < CC; ++c) xv[c] = xb[c * NN];

    if (eblk == 0) {
#pragma unroll
        for (int d = 0; d < DD; ++d) {
            float sq = bq[d], sk = bk[d];
#pragma unroll
            for (int c = 0; c < CC; ++c) {
                sq += Wq[d * CC + c] * xv[c];
                sk += Wk[d * CC + c] * xv[c];
            }
            qT[(b * DD + d) * NN + n] = sq;
            kT[(b * DD + d) * NN + n] = sk;
        }
    }

    // 16 v channels for this eblk, stored to vT[b][n][e] (contiguous per thread)
    float4* vout = (float4*)(vT + (size_t)(b * NN + n) * CC + eblk * 16);
#pragma unroll
    for (int e4 = 0; e4 < 4; ++e4) {
        float r[4];
#pragma unroll
        for (int u = 0; u < 4; ++u) {
            const int e = eblk * 16 + e4 * 4 + u;
            float sv = bv[e];
#pragma unroll
            for (int c = 0; c < CC; ++c) sv += Wv[e * CC + c] * xv[c];
            r[u] = sv;
        }
        float4 rv; rv.x = r[0]; rv.y = r[1]; rv.z = r[2]; rv.w = r[3];
        vout[e4] = rv;
    }
}

// ---------------------------------------------------------------------------
// Kernel 2: flash-style attention with rel-pos bias.
// Grid: B * (N/32) blocks; 256 threads = 4 waves; wave owns 8 queries.
// Key tiles of 64 == one image row (row_m uniform, col_m = lane).
// Lane = output channel in the PV phase.
// ---------------------------------------------------------------------------
__global__ __launch_bounds__(256) void attn_kernel(
    const float* __restrict__ qT, const float* __restrict__ kT,
    const float* __restrict__ vT, float* __restrict__ out)
{
    const int blk  = blockIdx.x;            // 0..511
    const int b    = blk >> 7;              // /128
    const int qt   = blk & 127;             // query tile: n in [qt*32, qt*32+32)
    const int tid  = threadIdx.x;
    const int wv   = tid >> 6;              // wave 0..3
    const int lane = tid & 63;

    const int rowq    = qt >> 1;                    // row of all 32 queries
    const int colbase = ((qt & 1) << 5) + wv * 8;   // col of this wave's qi=0

    __shared__ float qs[32 * 8];        // [qslot][d]
    __shared__ float ks[8 * 64];        // [d][j]
    __shared__ float vs[64 * 64];       // [j][c]
    __shared__ float wsm[4 * 8 * 64];   // [wave][qi][j]  (per-wave private)

    // stage q once
    if (tid < 256) {
        const int qslot = tid >> 3, d = tid & 7;
        qs[tid] = qT[(b * DD + d) * NN + qt * 32 + qslot];
    }

    float acc[8], mrun[8], lrun[8], alpha[8];
#pragma unroll
    for (int qi = 0; qi < 8; ++qi) { acc[qi] = 0.f; mrun[qi] = -1e30f; lrun[qi] = 0.f; }

    for (int t = 0; t < 64; ++t) {
        __syncthreads();   // previous tile's compute done (and q staged on t=0)
        // stage k-tile [8][64]
        {
            const int i = tid, i2 = tid + 256;
            ks[i]  = kT[(b * DD + (i  >> 6)) * NN + t * 64 + (i  & 63)];
            ks[i2] = kT[(b * DD + (i2 >> 6)) * NN + t * 64 + (i2 & 63)];
        }
        // stage v-tile [64][64] via float4
        {
            const float4* vsrc = (const float4*)(vT + (size_t)(b * NN + t * 64) * CC);
            float4* vdst = (float4*)vs;
#pragma unroll
            for (int i = 0; i < 4; ++i) vdst[tid + i * 256] = vsrc[tid + i * 256];
        }
        __syncthreads();

        // ---- phase 1: scores + online softmax (lane = key j) ----
        const float k0 = ks[0 * 64 + lane] + (float)lane;          // fold col_j
        const float k1 = ks[1 * 64 + lane] + (float)(t - rowq);    // fold row_j-row_q
        const float k2 = ks[2 * 64 + lane];
        const float k3 = ks[3 * 64 + lane];
        const float k4 = ks[4 * 64 + lane];
        const float k5 = ks[5 * 64 + lane];
        const float k6 = ks[6 * 64 + lane];
        const float k7 = ks[7 * 64 + lane];

#pragma unroll
        for (int qi = 0; qi < 8; ++qi) {
            const int qslot = wv * 8 + qi;
            const float4 qa = *(const float4*)&qs[qslot * 8];
            const float4 qb = *(const float4*)&qs[qslot * 8 + 4];
            const float colq = (float)(colbase + qi);
            float s = qa.x * (k0 - colq) + qa.y * k1 + qa.z * k2 + qa.w * k3
                    + qb.x * k4 + qb.y * k5 + qb.z * k6 + qb.w * k7;
            // all-lane max
            float tm = s;
#pragma unroll
            for (int off = 1; off < 64; off <<= 1) tm = fmaxf(tm, __shfl_xor(tm, off, 64));
            const float newm = fmaxf(mrun[qi], tm);
            const float al = __expf(mrun[qi] - newm);
            const float w  = __expf(s - newm);
            float ts = w;
#pragma unroll
            for (int off = 1; off < 64; off <<= 1) ts += __shfl_xor(ts, off, 64);
            lrun[qi]  = lrun[qi] * al + ts;
            mrun[qi]  = newm;
            alpha[qi] = al;
            wsm[wv * 512 + qi * 64 + lane] = w;
        }

        // ---- phase 2: PV accumulate (lane = channel c) ----
#pragma unroll
        for (int qi = 0; qi < 8; ++qi) acc[qi] *= alpha[qi];
#pragma unroll 4
        for (int jc = 0; jc < 16; ++jc) {
            const float v0 = vs[(jc * 4 + 0) * 64 + lane];
            const float v1 = vs[(jc * 4 + 1) * 64 + lane];
            const float v2 = vs[(jc * 4 + 2) * 64 + lane];
            const float v3 = vs[(jc * 4 + 3) * 64 + lane];
#pragma unroll
            for (int qi = 0; qi < 8; ++qi) {
                const float4 w4 = *(const float4*)&wsm[wv * 512 + qi * 64 + jc * 4];
                acc[qi] += w4.x * v0 + w4.y * v1 + w4.z * v2 + w4.w * v3;
            }
        }
    }

    // epilogue: out[b][c][n] with c = lane
#pragma unroll
    for (int qi = 0; qi < 8; ++qi) {
        const int n = qt * 32 + wv * 8 + qi;
        out[(size_t)(b * CC + lane) * NN + n] = acc[qi] / lrun[qi];
    }
}

extern "C" void kernel_launch(void* const* d_in, const int* in_sizes, int n_in,
                              void* d_out, int out_size, void* d_ws, size_t ws_size,
                              hipStream_t stream) {
    const float* x  = (const float*)d_in[0];
    const float* Wq = (const float*)d_in[1];
    const float* bq = (const float*)d_in[2];
    const float* Wk = (const float*)d_in[3];
    const float* bk = (const float*)d_in[4];
    const float* Wv = (const float*)d_in[5];
    const float* bv = (const float*)d_in[6];
    float* out = (float*)d_out;

    float* ws = (float*)d_ws;
    float* qT = ws;                       // B*8*N
    float* kT = ws + BB * DD * NN;        // B*8*N
    float* vT = ws + 2 * BB * DD * NN;    // B*N*C

    qkv_kernel<<<256, 256, 0, stream>>>(x, Wq, bq, Wk, bk, Wv, bv, qT, kT, vT);
    attn_kernel<<<BB * (NN / 32), 256, 0, stream>>>(qT, kT, vT, out);
}

// Round 2
// 378.589 us; speedup vs baseline: 1.3752x; 1.3752x over previous
//
#include <hip/hip_runtime.h>

// Problem constants (B,C,H,W = 4,64,64,64; d = 8)
#define BB 4
#define CC 64
#define HH 64
#define WW 64
#define NN 4096   // H*W
#define DD 8

#define WAVES 8   // waves per attn block
#define QPW 4     // queries per wave; WAVES*QPW = 32 queries/block

// ws layout (floats): qT [B][8][N] | kT [B][8][N] | vT [B][N][C]

// ---------------------------------------------------------------------------
// Kernel 1: QKV projection (1x1 convs). Blocks 0..255: 16 v-channels each
// (eblk = blk&3). Blocks 256..319: q+k (8 channels each). Balanced work.
// ---------------------------------------------------------------------------
__global__ __launch_bounds__(256) void qkv_kernel(
    const float* __restrict__ x,
    const float* __restrict__ Wq, const float* __restrict__ bq,
    const float* __restrict__ Wk, const float* __restrict__ bk,
    const float* __restrict__ Wv, const float* __restrict__ bv,
    float* __restrict__ qT, float* __restrict__ kT, float* __restrict__ vT)
{
    const int work = blockIdx.x;
    int idx;
    if (work < 256) idx = (work >> 2) * 256 + threadIdx.x;
    else            idx = (work - 256) * 256 + threadIdx.x;
    const int b = idx >> 12;
    const int n = idx & (NN - 1);

    const float* xb = x + (size_t)b * CC * NN + n;
    float xv[CC];
#pragma unroll
    for (int c = 0; c < CC; ++c) xv[c] = xb[c * NN];

    if (work >= 256) {
#pragma unroll
        for (int d = 0; d < DD; ++d) {
            float sq = bq[d], sk = bk[d];
#pragma unroll
            for (int c = 0; c < CC; ++c) {
                sq += Wq[d * CC + c] * xv[c];
                sk += Wk[d * CC + c] * xv[c];
            }
            qT[(b * DD + d) * NN + n] = sq;
            kT[(b * DD + d) * NN + n] = sk;
        }
        return;
    }

    const int eblk = work & 3;
    float4* vout = (float4*)(vT + (size_t)(b * NN + n) * CC + eblk * 16);
#pragma unroll
    for (int e4 = 0; e4 < 4; ++e4) {
        float r[4];
#pragma unroll
        for (int u = 0; u < 4; ++u) {
            const int e = eblk * 16 + e4 * 4 + u;
            float sv = bv[e];
#pragma unroll
            for (int c = 0; c < CC; ++c) sv += Wv[e * CC + c] * xv[c];
            r[u] = sv;
        }
        float4 rv; rv.x = r[0]; rv.y = r[1]; rv.z = r[2]; rv.w = r[3];
        vout[e4] = rv;
    }
}

// ---------------------------------------------------------------------------
// Kernel 2: two-pass attention with rel-pos bias.
// Grid: B * (N/32) = 512 blocks; 512 threads = 8 waves; wave owns 4 queries.
// Pass A: exact per-query max (K straight from global, no syncs, one
//         butterfly per query at the end).
// Pass B: recompute scores, w = exp(s-M), per-lane denominator, PV via
//         LDS transpose (lane = key j in score phase, lane = channel c in PV).
// Key tiles of 64 == one image row (row_j uniform per tile, col_j = lane).
// ---------------------------------------------------------------------------
__global__ __launch_bounds__(512, 4) void attn_kernel(
    const float* __restrict__ qT, const float* __restrict__ kT,
    const float* __restrict__ vT, float* __restrict__ out)
{
    const int blk  = blockIdx.x;            // 0..511
    const int b    = blk >> 7;
    const int qt   = blk & 127;             // 32-query tile
    const int tid  = threadIdx.x;
    const int wv   = tid >> 6;              // 0..7
    const int lane = tid & 63;

    const int qbase   = qt * 32;
    const int rowq    = qt >> 1;                     // image row of all 32 queries
    const int colbase = ((qt & 1) << 5) + wv * QPW;  // col of this wave's qi=0

    __shared__ float qs[32 * 8];            // [qslot][d]
    __shared__ float ks[8 * 64];            // [d][j]
    __shared__ float vs[64 * 64];           // [j][c]
    __shared__ float wsm[WAVES * QPW * 64]; // [wave][qi][j] (wave-private)

    if (tid < 256) {
        const int qslot = tid >> 3, d = tid & 7;
        qs[tid] = qT[(b * DD + d) * NN + qbase + qslot];
    }
    __syncthreads();

    // q fragments into registers (broadcast reads)
    float q[QPW][8];
#pragma unroll
    for (int qi = 0; qi < QPW; ++qi)
#pragma unroll
        for (int d = 0; d < 8; ++d) q[qi][d] = qs[(wv * QPW + qi) * 8 + d];

    const float flane = (float)lane;

    // ---------------- Pass A: exact max per query ----------------
    float M[QPW];
#pragma unroll
    for (int qi = 0; qi < QPW; ++qi) M[qi] = -1e30f;

    const float* kb = kT + (size_t)b * DD * NN + lane;
    for (int t = 0; t < 64; ++t) {
        const float k0 = kb[0 * NN + t * 64] + flane;
        const float k1 = kb[1 * NN + t * 64] + (float)(t - rowq);
        const float k2 = kb[2 * NN + t * 64];
        const float k3 = kb[3 * NN + t * 64];
        const float k4 = kb[4 * NN + t * 64];
        const float k5 = kb[5 * NN + t * 64];
        const float k6 = kb[6 * NN + t * 64];
        const float k7 = kb[7 * NN + t * 64];
#pragma unroll
        for (int qi = 0; qi < QPW; ++qi) {
            const float s = q[qi][0] * (k0 - (float)(colbase + qi)) + q[qi][1] * k1
                          + q[qi][2] * k2 + q[qi][3] * k3 + q[qi][4] * k4
                          + q[qi][5] * k5 + q[qi][6] * k6 + q[qi][7] * k7;
            M[qi] = fmaxf(M[qi], s);
        }
    }
#pragma unroll
    for (int qi = 0; qi < QPW; ++qi)
#pragma unroll
        for (int off = 1; off < 64; off <<= 1)
            M[qi] = fmaxf(M[qi], __shfl_xor(M[qi], off, 64));

    // ---------------- Pass B: exp + denominator + PV ----------------
    float acc[QPW], l[QPW];
#pragma unroll
    for (int qi = 0; qi < QPW; ++qi) { acc[qi] = 0.f; l[qi] = 0.f; }

    for (int t = 0; t < 64; ++t) {
        __syncthreads();
        // stage K tile [8][64]
        ks[tid] = kT[(b * DD + (tid >> 6)) * NN + t * 64 + (tid & 63)];
        // stage V tile [64][64]
        {
            const float4* vsrc = (const float4*)(vT + (size_t)(b * NN + t * 64) * CC);
            float4* vdst = (float4*)vs;
            vdst[tid]       = vsrc[tid];
            vdst[tid + 512] = vsrc[tid + 512];
        }
        __syncthreads();

        const float k0 = ks[0 * 64 + lane] + flane;
        const float k1 = ks[1 * 64 + lane] + (float)(t - rowq);
        const float k2 = ks[2 * 64 + lane];
        const float k3 = ks[3 * 64 + lane];
        const float k4 = ks[4 * 64 + lane];
        const float k5 = ks[5 * 64 + lane];
        const float k6 = ks[6 * 64 + lane];
        const float k7 = ks[7 * 64 + lane];

#pragma unroll
        for (int qi = 0; qi < QPW; ++qi) {
            const float s = q[qi][0] * (k0 - (float)(colbase + qi)) + q[qi][1] * k1
                          + q[qi][2] * k2 + q[qi][3] * k3 + q[qi][4] * k4
                          + q[qi][5] * k5 + q[qi][6] * k6 + q[qi][7] * k7;
            const float w = __expf(s - M[qi]);   // <= 1, no overflow
            l[qi] += w;
            wsm[(wv * QPW + qi) * 64 + lane] = w;
        }

        // PV: lane = channel c
#pragma unroll 4
        for (int jc = 0; jc < 16; ++jc) {
            const float v0 = vs[(jc * 4 + 0) * 64 + lane];
            const float v1 = vs[(jc * 4 + 1) * 64 + lane];
            const float v2 = vs[(jc * 4 + 2) * 64 + lane];
            const float v3 = vs[(jc * 4 + 3) * 64 + lane];
#pragma unroll
            for (int qi = 0; qi < QPW; ++qi) {
                const float4 w4 = *(const float4*)&wsm[(wv * QPW + qi) * 64 + jc * 4];
                acc[qi] += w4.x * v0 + w4.y * v1 + w4.z * v2 + w4.w * v3;
            }
        }
    }

#pragma unroll
    for (int qi = 0; qi < QPW; ++qi)
#pragma unroll
        for (int off = 1; off < 64; off <<= 1)
            l[qi] += __shfl_xor(l[qi], off, 64);

#pragma unroll
    for (int qi = 0; qi < QPW; ++qi) {
        const int n = qbase + wv * QPW + qi;
        out[(size_t)(b * CC + lane) * NN + n] = acc[qi] / l[qi];
    }
}

extern "C" void kernel_launch(void* const* d_in, const int* in_sizes, int n_in,
                              void* d_out, int out_size, void* d_ws, size_t ws_size,
                              hipStream_t stream) {
    const float* x  = (const float*)d_in[0];
    const float* Wq = (const float*)d_in[1];
    const float* bq = (const float*)d_in[2];
    const float* Wk = (const float*)d_in[3];
    const float* bk = (const float*)d_in[4];
    const float* Wv = (const float*)d_in[5];
    const float* bv = (const float*)d_in[6];
    float* out = (float*)d_out;

    float* ws = (float*)d_ws;
    float* qT = ws;                       // B*8*N
    float* kT = ws + BB * DD * NN;        // B*8*N
    float* vT = ws + 2 * BB * DD * NN;    // B*N*C

    qkv_kernel<<<320, 256, 0, stream>>>(x, Wq, bq, Wk, bk, Wv, bv, qT, kT, vT);
    attn_kernel<<<BB * (NN / 32), 512, 0, stream>>>(qT, kT, vT, out);
}

// Round 3
// 140.698 us; speedup vs baseline: 3.7002x; 2.6908x over previous
//
#include <hip/hip_runtime.h>

// B,C,H,W = 4,64,64,64 ; N = 4096 ; d = 8
#define BB 4
#define CC 64
#define NN 4096

typedef __attribute__((ext_vector_type(8))) short short8;
typedef __attribute__((ext_vector_type(4))) float f32x4;

__device__ inline ushort f2bf(float x) {                 // RNE float->bf16
    unsigned u = __float_as_uint(x);
    return (ushort)((u + 0x7fff + ((u >> 16) & 1)) >> 16);
}
__device__ inline float bf2f(ushort h) { return __uint_as_float(((unsigned)h) << 16); }

// ws layout (ushort):
//   qTp [B][N][32]  : q0..q7, q0h,q1h,q0l,q1l, 0*20              (1 MB)
//   kTp [B][N][32]  : k0..k7, col,row,col,row, 0*20              (1 MB)
//   vsw [B][64 tiles][2 ksteps * 5 groups][64 lanes][8 halves]   (2.62 MB)
//     B-frag swizzled: lane quad*16+nn holds v'[s*32+quad*8+jj][16g+nn],
//     channel 64 = 1.0 (denominator ones-column), 65..79 = 0.

// ---------------------------------------------------------------------------
// Kernel 1: QKV projection. Blocks 0..255: 16 v-channels (eblk=blk&3) written
// bf16-swizzled; eblk==3 also writes the ones-group. Blocks 256..319: q/k with
// rel-pos fold + hi/lo split, zero-padded to 32 channels.
// ---------------------------------------------------------------------------
__global__ __launch_bounds__(256) void qkv_kernel(
    const float* __restrict__ x,
    const float* __restrict__ Wq, const float* __restrict__ bq,
    const float* __restrict__ Wk, const float* __restrict__ bk,
    const float* __restrict__ Wv, const float* __restrict__ bv,
    ushort* __restrict__ qTp, ushort* __restrict__ kTp, ushort* __restrict__ vsw)
{
    const int work = blockIdx.x;
    const int idx  = (work < 256) ? (work >> 2) * 256 + threadIdx.x
                                  : (work - 256) * 256 + threadIdx.x;
    const int b = idx >> 12;
    const int n = idx & (NN - 1);

    const float* xb = x + (size_t)b * CC * NN + n;
    float xv[CC];
#pragma unroll
    for (int c = 0; c < CC; ++c) xv[c] = xb[c * NN];

    if (work >= 256) {
        float q[8], k[8];
#pragma unroll
        for (int d = 0; d < 8; ++d) {
            float sq = bq[d], sk = bk[d];
#pragma unroll
            for (int c = 0; c < CC; ++c) {
                sq += Wq[d * CC + c] * xv[c];
                sk += Wk[d * CC + c] * xv[c];
            }
            q[d] = sq; k[d] = sk;
        }
        ushort hq[32], hk[32];
#pragma unroll
        for (int i = 0; i < 32; ++i) { hq[i] = 0; hk[i] = 0; }
#pragma unroll
        for (int d = 0; d < 8; ++d) { hq[d] = f2bf(q[d]); hk[d] = f2bf(k[d]); }
        // hi/lo split of q0,q1 against exact integer col/row
        hq[8]  = hq[0];                               // q0 hi
        hq[9]  = hq[1];                               // q1 hi
        hq[10] = f2bf(q[0] - bf2f(hq[0]));            // q0 lo
        hq[11] = f2bf(q[1] - bf2f(hq[1]));            // q1 lo
        const float col = (float)(n & 63), row = (float)(n >> 6);
        hk[8] = f2bf(col); hk[9] = f2bf(row); hk[10] = hk[8]; hk[11] = hk[9];

        uint4* dq = (uint4*)(qTp + (size_t)(b * NN + n) * 32);
        uint4* dk = (uint4*)(kTp + (size_t)(b * NN + n) * 32);
        const uint4* sq4 = (const uint4*)hq;
        const uint4* sk4 = (const uint4*)hk;
#pragma unroll
        for (int i = 0; i < 4; ++i) { dq[i] = sq4[i]; dk[i] = sk4[i]; }
        return;
    }

    const int eblk = work & 3;
    const int t = n >> 6, j = n & 63;
    const int s = j >> 5, qd = (j >> 3) & 3, jj = j & 7;
    const size_t fb = ((size_t)(b * 64 + t) * 640 + (size_t)(s * 5 + eblk) * 64 + qd * 16) * 8 + jj;
#pragma unroll
    for (int u = 0; u < 16; ++u) {
        const int e = eblk * 16 + u;
        float sv = bv[e];
#pragma unroll
        for (int c = 0; c < CC; ++c) sv += Wv[e * CC + c] * xv[c];
        vsw[fb + (size_t)u * 8] = f2bf(sv);
    }
    if (eblk == 3) {   // ones-group g=4: channel 64 = 1.0, 65..79 = 0
        const size_t fo = ((size_t)(b * 64 + t) * 640 + (size_t)(s * 5 + 4) * 64 + qd * 16) * 8 + jj;
        vsw[fo] = 0x3F80;
#pragma unroll
        for (int u = 1; u < 16; ++u) vsw[fo + (size_t)u * 8] = 0;
    }
}

// ---------------------------------------------------------------------------
// Kernel 2: MFMA attention. 1024 blocks (B x N/16), 256 threads = 4 waves.
// All waves share the block's 16 queries; keys split 4-way (16 tiles each).
// Pass A: S^T = K'.Q^T via MFMA -> exact max (lane = query in C-layout).
// Pass B: recompute S^T, w = exp(s-M) -> bf16 -> LDS P[q][j] (pack-4 b64
// writes, b128 A-frag reads) -> PV MFMA with swizzled V' (+ ones channel
// giving the denominator). Cross-wave combine in LDS at the end only.
// ---------------------------------------------------------------------------
__global__ __launch_bounds__(256, 4) void attn_kernel(
    const ushort* __restrict__ qTp, const ushort* __restrict__ kTp,
    const ushort* __restrict__ vsw, float* __restrict__ out)
{
    const int blk = blockIdx.x;
    const int b   = blk >> 8;
    const int nq  = (blk & 255) << 4;
    const int tid = threadIdx.x;
    const int wv   = tid >> 6;
    const int lane = tid & 63;
    const int nn   = lane & 15;
    const int quad = lane >> 4;

    __shared__ ushort Pbuf[4][16 * 72];   // per-wave P tile, stride 72 halves
    __shared__ float  Mx[4][16];
    __shared__ float  Cb[4][1280];        // per-wave C-layout partials (5 groups)
    __shared__ float  dn[16];

    // Q B-frag: lane holds q-channels quad*8..+8 of query nq+nn
    const short8 qf = *(const short8*)(qTp + ((size_t)(b * NN + nq + nn) * 32 + quad * 8));
    const ushort* kb = kTp + (size_t)b * NN * 32;

    // ---------------- Pass A: exact max ----------------
    float Ml = -1e30f;
    for (int t8 = 0; t8 < 16; ++t8) {
        const int t = wv * 16 + t8;
#pragma unroll
        for (int kg = 0; kg < 4; ++kg) {
            const short8 kf = *(const short8*)(kb + ((size_t)(t * 64 + kg * 16 + nn) * 32 + quad * 8));
            f32x4 S = __builtin_amdgcn_mfma_f32_16x16x32_bf16(kf, qf, (f32x4){0.f,0.f,0.f,0.f}, 0, 0, 0);
            Ml = fmaxf(Ml, fmaxf(fmaxf(S[0], S[1]), fmaxf(S[2], S[3])));
        }
    }
    Ml = fmaxf(Ml, __shfl_xor(Ml, 16, 64));
    Ml = fmaxf(Ml, __shfl_xor(Ml, 32, 64));
    if (quad == 0) Mx[wv][nn] = Ml;
    __syncthreads();
    const float M = fmaxf(fmaxf(Mx[0][nn], Mx[1][nn]), fmaxf(Mx[2][nn], Mx[3][nn]));

    // ---------------- Pass B: exp + PV ----------------
    f32x4 acc[5];
#pragma unroll
    for (int g = 0; g < 5; ++g) acc[g] = (f32x4){0.f,0.f,0.f,0.f};

    ushort* Pw = Pbuf[wv];
    for (int t8 = 0; t8 < 16; ++t8) {
        const int t = wv * 16 + t8;
#pragma unroll
        for (int kg = 0; kg < 4; ++kg) {
            const short8 kf = *(const short8*)(kb + ((size_t)(t * 64 + kg * 16 + nn) * 32 + quad * 8));
            f32x4 S = __builtin_amdgcn_mfma_f32_16x16x32_bf16(kf, qf, (f32x4){0.f,0.f,0.f,0.f}, 0, 0, 0);
            // lane = query nn; regs = keys kg*16+quad*4 .. +3 (consecutive)
            const float w0 = __expf(S[0] - M), w1 = __expf(S[1] - M);
            const float w2 = __expf(S[2] - M), w3 = __expf(S[3] - M);
            uint2 pk;
            pk.x = (unsigned)f2bf(w0) | ((unsigned)f2bf(w1) << 16);
            pk.y = (unsigned)f2bf(w2) | ((unsigned)f2bf(w3) << 16);
            *(uint2*)(Pw + nn * 72 + kg * 16 + quad * 4) = pk;
        }
        // PV: A = P[q][j] (b128 frags), B = swizzled V' from global (L2)
#pragma unroll
        for (int s = 0; s < 2; ++s) {
            const short8 af = *(const short8*)(Pw + nn * 72 + s * 32 + quad * 8);
            const ushort* vb = vsw + ((size_t)(b * 64 + t) * 640 + (size_t)s * 320) * 8;
#pragma unroll
            for (int g = 0; g < 5; ++g) {
                const short8 vf = *(const short8*)(vb + ((size_t)(g * 64 + lane)) * 8);
                acc[g] = __builtin_amdgcn_mfma_f32_16x16x32_bf16(af, vf, acc[g], 0, 0, 0);
            }
        }
    }

    // ---------------- combine across waves ----------------
#pragma unroll
    for (int g = 0; g < 5; ++g)
#pragma unroll
        for (int r = 0; r < 4; ++r)
            Cb[wv][(g * 4 + r) * 64 + lane] = acc[g][r];
    __syncthreads();

    if (tid < 16) {   // denominator: group 4, channel col 0, query tid
        const int q = tid;
        const int src = (16 + (q & 3)) * 64 + (q >> 2) * 16;
        dn[q] = Cb[0][src] + Cb[1][src] + Cb[2][src] + Cb[3][src];
    }
    __syncthreads();

    for (int e = tid; e < 1024; e += 256) {
        const int q = e & 15, c = e >> 4;
        const int src = ((c >> 4) * 4 + (q & 3)) * 64 + (q >> 2) * 16 + (c & 15);
        const float v = Cb[0][src] + Cb[1][src] + Cb[2][src] + Cb[3][src];
        out[(size_t)(b * CC + c) * NN + nq + q] = v / dn[q];
    }
}

extern "C" void kernel_launch(void* const* d_in, const int* in_sizes, int n_in,
                              void* d_out, int out_size, void* d_ws, size_t ws_size,
                              hipStream_t stream) {
    const float* x  = (const float*)d_in[0];
    const float* Wq = (const float*)d_in[1];
    const float* bq = (const float*)d_in[2];
    const float* Wk = (const float*)d_in[3];
    const float* bk = (const float*)d_in[4];
    const float* Wv = (const float*)d_in[5];
    const float* bv = (const float*)d_in[6];
    float* out = (float*)d_out;

    ushort* ws  = (ushort*)d_ws;
    ushort* qTp = ws;                          // B*N*32 halves
    ushort* kTp = ws + (size_t)BB * NN * 32;   // B*N*32 halves
    ushort* vsw = ws + (size_t)2 * BB * NN * 32; // B*64*640*8 halves

    qkv_kernel<<<320, 256, 0, stream>>>(x, Wq, bq, Wk, bk, Wv, bv, qTp, kTp, vsw);
    attn_kernel<<<BB * 256, 256, 0, stream>>>(qTp, kTp, vsw, out);
}